// Round 12
// baseline (243.064 us; speedup 1.0000x reference)
//
#include <hip/hip_runtime.h>
#include <math.h>

#define BB 32
#define CC 256
#define OO 256
#define HW 56
#define SP (HW*HW)      // 3136
#define KK 4
#define HID 129
#define TEMP 34.0f
#define PROW 58                       // padded rows/cols (1-halo each side)
#define PLANE (PROW*PROW*32)          // u16 per (b,cb) plane = 107648
#define PLANEB (PROW*PROW*64)         // bytes per (b,cb) plane = 215296
#define NSLOT 348                     // 6*58 real slots per staged window
#define QSLOT 350                     // slots incl. 2 dummy pad slots per q-plane
#define QSTRIDE (QSLOT*16)            // 5600 B per q-plane in LDS (kg banks {0,24,16,8})
#define NPIECE (4*QSLOT)              // 1400 16B pieces per buffer
#define BUFB (4*QSTRIDE)              // 22400 B per LDS buffer

typedef unsigned short u16;
typedef unsigned int uint32;
typedef __attribute__((ext_vector_type(8))) short bf16x8;
typedef __attribute__((ext_vector_type(4))) float f32x4;

__device__ __forceinline__ u16 f2bf(float f) {
    union { float f; uint32 u; } v; v.f = f;
    uint32 r = v.u + 0x7FFF + ((v.u >> 16) & 1);
    return (u16)(r >> 16);
}

__device__ __forceinline__ void gload16(const void* g, void* l) {
    __builtin_amdgcn_global_load_lds(
        (const __attribute__((address_space(1))) unsigned int*)g,
        (__attribute__((address_space(3))) unsigned int*)l, 16, 0, 0);
}

// ---------------- Stage 1: fused transpose->bf16 (zero-padded) + mix pooling ----
__global__ __launch_bounds__(256) void trans_pool(const float* __restrict__ x,
                                                  u16* __restrict__ xt,
                                                  float* __restrict__ pooled) {
    const int cb = blockIdx.x, b = blockIdx.y;
    const int tid = threadIdx.x;
    const int lane = tid & 63, wave = tid >> 6;
    const float* xp = x + ((size_t)b * CC + cb * 32) * SP;
    u16* xtb = xt + (size_t)(b * 8 + cb) * PLANE;

    // zero the 228 halo slots
    if (tid < 228) {
        int slot;
        if (tid < 58)       slot = tid;                       // row 0
        else if (tid < 116) slot = 57 * 58 + (tid - 58);      // row 57
        else if (tid < 172) slot = (tid - 116 + 1) * 58;      // col 0, rows 1..56
        else                slot = (tid - 172 + 1) * 58 + 57; // col 57, rows 1..56
        bf16x8 z = {};
        #pragma unroll
        for (int j = 0; j < 4; ++j)
            *(bf16x8*)&xtb[(size_t)slot * 32 + j * 8] = z;
    }

    float psum[32], pmax[32];
    #pragma unroll
    for (int c = 0; c < 32; ++c) { psum[c] = 0.f; pmax[c] = -INFINITY; }

    for (int p0 = 0; p0 < SP; p0 += 256) {
        const int p = p0 + tid;
        const bool v = p < SP;
        const int pc = v ? p : (SP - 1);
        u16 ob[32];
        #pragma unroll
        for (int c = 0; c < 32; ++c) {
            const float vv = xp[(size_t)c * SP + pc];
            if (v) { psum[c] += vv; pmax[c] = fmaxf(pmax[c], vv); }
            ob[c] = f2bf(vv);
        }
        if (v) {
            const int slot = (p / 56 + 1) * 58 + (p % 56 + 1);
            #pragma unroll
            for (int j = 0; j < 4; ++j)
                *(bf16x8*)&xtb[(size_t)slot * 32 + j * 8] = *(bf16x8*)&ob[j * 8];
        }
    }
    #pragma unroll
    for (int c = 0; c < 32; ++c) {
        #pragma unroll
        for (int off = 32; off >= 1; off >>= 1) {
            psum[c] += __shfl_xor(psum[c], off, 64);
            pmax[c] = fmaxf(pmax[c], __shfl_xor(pmax[c], off, 64));
        }
    }
    __shared__ float ssum[4][32];
    __shared__ float smax[4][32];
    if (lane == 0) {
        #pragma unroll
        for (int c = 0; c < 32; ++c) { ssum[wave][c] = psum[c]; smax[wave][c] = pmax[c]; }
    }
    __syncthreads();
    if (tid < 32) {
        const float s = ssum[0][tid] + ssum[1][tid] + ssum[2][tid] + ssum[3][tid];
        const float m = fmaxf(fmaxf(smax[0][tid], smax[1][tid]),
                              fmaxf(smax[2][tid], smax[3][tid]));
        pooled[b * (2 * CC) + cb * 32 + tid]      = s / (float)SP;
        pooled[b * (2 * CC) + CC + cb * 32 + tid] = m;
    }
}

// ---------------- Stage 2: attention MLP + softmax + agg bias ----------------
__global__ __launch_bounds__(256) void attn_kernel(const float* __restrict__ pooled,
                                                   const float* __restrict__ w1,
                                                   const float* __restrict__ w2,
                                                   const float* __restrict__ b2,
                                                   const float* __restrict__ bias_k,
                                                   float* __restrict__ attn,
                                                   float* __restrict__ agg_b) {
    const int b = blockIdx.x;
    const int tid = threadIdx.x;
    __shared__ float p[2 * CC];
    __shared__ float h[HID];
    __shared__ float a[KK];
    for (int i = tid; i < 2 * CC; i += 256) p[i] = pooled[b * 2 * CC + i];
    __syncthreads();
    if (tid < HID) {
        float s = 0.f;
        const float* w1r = w1 + (size_t)tid * (2 * CC);
        for (int c = 0; c < 2 * CC; ++c) s = fmaf(p[c], w1r[c], s);
        h[tid] = fmaxf(s, 0.f);
    }
    __syncthreads();
    if (tid == 0) {
        float lg[KK];
        float m = -INFINITY;
        for (int k = 0; k < KK; ++k) {
            float s = b2[k];
            for (int i = 0; i < HID; ++i) s = fmaf(h[i], w2[k * HID + i], s);
            lg[k] = s / TEMP;
            m = fmaxf(m, lg[k]);
        }
        float den = 0.f;
        for (int k = 0; k < KK; ++k) { lg[k] = expf(lg[k] - m); den += lg[k]; }
        for (int k = 0; k < KK; ++k) { a[k] = lg[k] / den; attn[b * KK + k] = a[k]; }
    }
    __syncthreads();
    if (tid < OO) {
        float s = 0.f;
        #pragma unroll
        for (int k = 0; k < KK; ++k) s = fmaf(a[k], bias_k[k * OO + tid], s);
        agg_b[b * OO + tid] = s;
    }
}

// ---------------- Stage 2b: aggregate weights -> bf16, layout wT[b][uv][o][c] ----
__global__ __launch_bounds__(256) void agg_kernel(const float* __restrict__ weight,
                                                  const float* __restrict__ attn,
                                                  u16* __restrict__ wT) {
    const int o = blockIdx.x;
    const int c = threadIdx.x;
    __shared__ float at[BB * KK];
    if (threadIdx.x < BB * KK) at[threadIdx.x] = attn[threadIdx.x];
    __syncthreads();
    float w[KK][9];
    #pragma unroll
    for (int k = 0; k < KK; ++k)
        #pragma unroll
        for (int uv = 0; uv < 9; ++uv)
            w[k][uv] = weight[(size_t)((k * OO + o) * CC + c) * 9 + uv];
    for (int b = 0; b < BB; ++b) {
        const float a0 = at[b*KK+0], a1 = at[b*KK+1], a2 = at[b*KK+2], a3 = at[b*KK+3];
        #pragma unroll
        for (int uv = 0; uv < 9; ++uv) {
            float s = a0 * w[0][uv] + a1 * w[1][uv] + a2 * w[2][uv] + a3 * w[3][uv];
            wT[(size_t)((b * 9 + uv) * OO + o) * CC + c] = f2bf(s);
        }
    }
}

// ---------------- Stage 3: MFMA implicit-GEMM conv — occupancy build ----------------
// Grid 1792, XCD-pinned: b = (id&7) + 8*((id>>3)/56). Block tile 64o x 224p,
// 4 waves (2M x 2N), wave 32x112 (M_rep=2 -> acc 56 AGPR). ~126 unified regs
// -> __launch_bounds__(256,3): 3 blocks/CU co-resident (12 waves/CU, was 6) with
// INDEPENDENT barriers — the R4-R11 plateau was 2-wave/SIMD occupancy starvation
// (each wave lived ~70us for ~4us of work; no schedule fixes that).
// x staged via global_load_lds into linear LDS [q][350 slots]x16B; q-plane
// stride 5600B so kg bank offsets {0,24,16,8} kill the 4-way read conflict.
// Stage issues for chunk cb+1 spread across phases uv=0..5 of chunk cb.
__global__ __launch_bounds__(256, 3) void conv_mfma(const u16* __restrict__ xt,
                                                    const u16* __restrict__ wT,
                                                    const float* __restrict__ agg_b,
                                                    float* __restrict__ out) {
    const int id   = blockIdx.x;
    const int g    = id >> 3;
    const int b    = (id & 7) + 8 * (g / 56);
    const int tile = g % 56;
    const int px   = tile % 14, oy = tile / 14;
    const int tid  = threadIdx.x;
    const int lane = tid & 63, wave = tid >> 6;
    const int wm = wave & 1, wn = wave >> 1;
    const int l15 = lane & 15, kg = lane >> 4;
    const int p0 = px * 224;

    __shared__ char xs[2][BUFB];   // 2 x 22400 B

    // stage-piece map: piece i = k*256 + tid (i < 1400); LDS byte = i*16 (linear,
    // satisfies gload_lds wave-uniform-base + lane*16). Global: q = i/350,
    // slot = i%350 -> byte (px*232 + slot)*64 + q*16 (slots 348/349 = dummies).
    uint32 soff[6]; bool sact[6];
    #pragma unroll
    for (int k = 0; k < 6; ++k) {
        const int i = k * 256 + tid;
        sact[k] = (i < NPIECE);
        const int q = i / QSLOT, slot = i % QSLOT;
        soff[k] = (uint32)((px * 232 + slot) * 64 + q * 16);
    }

    // B-read base byte per n-fragment: kg*QSTRIDE + S*16,
    // S = (n/56+1)*58 + n%56+1 (window-relative slot of output pixel)
    int bboff[7];
    #pragma unroll
    for (int nf = 0; nf < 7; ++nf) {
        const int n = wn * 112 + nf * 16 + l15;
        const int S = (n / 56 + 1) * 58 + (n % 56 + 1);
        bboff[nf] = kg * QSTRIDE + S * 16;
    }

    // A-operand: wT[b][uv][o][c], o = oy*64 + wm*32 + mf*16 + l15, c = c0 + kg*8
    const u16* wTb = wT + (size_t)b * 9 * OO * CC
                        + (size_t)(oy * 64 + wm * 32 + l15) * CC + kg * 8;

    f32x4 acc[2][7];
    #pragma unroll
    for (int mf = 0; mf < 2; ++mf)
        #pragma unroll
        for (int nf = 0; nf < 7; ++nf)
            acc[mf][nf] = (f32x4)0.f;

    const char* xgb = (const char*)xt + (size_t)(b * 8) * PLANEB;

    // prologue: stage chunk 0 into buf0
    #pragma unroll
    for (int k = 0; k < 6; ++k)
        if (sact[k]) gload16(xgb + soff[k], &xs[0][k * 4096 + wave * 1024]);
    __syncthreads();

    for (int cb = 0; cb < 8; ++cb) {
        const char* R = xs[cb & 1];
        char* W = xs[(cb & 1) ^ 1];
        const char* xg_next = xgb + (size_t)(cb + 1) * PLANEB;
        const int c0 = cb * 32;

        #pragma unroll
        for (int uv = 0; uv < 9; ++uv) {
            // spread next-chunk staging across phases 0..5
            if (uv < 6 && cb < 7) {
                if (sact[uv]) gload16(xg_next + soff[uv], &W[uv * 4096 + wave * 1024]);
            }
            bf16x8 av[2];
            #pragma unroll
            for (int mf = 0; mf < 2; ++mf)
                av[mf] = *(const bf16x8*)(wTb + (size_t)uv * OO * CC + mf * 16 * CC + c0);
            const int dby = ((uv / 3 - 1) * 58 + (uv % 3 - 1)) * 16;
            __builtin_amdgcn_s_setprio(1);
            #pragma unroll
            for (int nf = 0; nf < 7; ++nf) {
                const bf16x8 bv = *(const bf16x8*)(R + bboff[nf] + dby);
                #pragma unroll
                for (int mf = 0; mf < 2; ++mf)
                    acc[mf][nf] = __builtin_amdgcn_mfma_f32_16x16x32_bf16(av[mf], bv, acc[mf][nf], 0, 0, 0);
            }
            __builtin_amdgcn_s_setprio(0);
        }
        __syncthreads();   // staging queue already consumed; releases W
    }

    // epilogue: D row = kg*4 + r (-> o), col = l15 (-> p)
    const int obase = oy * 64 + wm * 32;
    float* outb = out + (size_t)b * OO * SP;
    #pragma unroll
    for (int mf = 0; mf < 2; ++mf) {
        #pragma unroll
        for (int r = 0; r < 4; ++r) {
            const int o = obase + mf * 16 + kg * 4 + r;
            const float bias = agg_b[b * OO + o];
            #pragma unroll
            for (int nf = 0; nf < 7; ++nf) {
                const int p = p0 + wn * 112 + nf * 16 + l15;
                outb[(size_t)o * SP + p] = acc[mf][nf][r] + bias;
            }
        }
    }
}

extern "C" void kernel_launch(void* const* d_in, const int* in_sizes, int n_in,
                              void* d_out, int out_size, void* d_ws, size_t ws_size,
                              hipStream_t stream) {
    const float* x      = (const float*)d_in[0];
    const float* weight = (const float*)d_in[1];
    const float* bias_k = (const float*)d_in[2];
    const float* w1     = (const float*)d_in[3];
    const float* w2     = (const float*)d_in[4];
    const float* b2     = (const float*)d_in[5];
    float* out = (float*)d_out;

    // workspace: x_t padded bf16 (55.1 MB) | wT bf16 (37.75 MB) | fp32 scratch
    u16* x_t = (u16*)d_ws;
    u16* wT  = x_t + (size_t)BB * 8 * PLANE;
    float* ws_f   = (float*)(wT + (size_t)BB * 9 * OO * CC);
    float* pooled = ws_f;
    float* attn   = ws_f + BB * 2 * CC;
    float* agg_b  = attn + BB * KK;

    trans_pool<<<dim3(8, BB), 256, 0, stream>>>(x, x_t, pooled);
    attn_kernel<<<BB, 256, 0, stream>>>(pooled, w1, w2, b2, bias_k, attn, agg_b);
    agg_kernel<<<OO, 256, 0, stream>>>(weight, attn, wT);
    conv_mfma<<<1792, 256, 0, stream>>>(x_t, wT, agg_b, out);
}

// Round 13
// 232.328 us; speedup vs baseline: 1.0462x; 1.0462x over previous
//
#include <hip/hip_runtime.h>
#include <math.h>

#define BB 32
#define CC 256
#define OO 256
#define HW 56
#define SP (HW*HW)      // 3136
#define KK 4
#define HID 129
#define TEMP 34.0f
#define PROW 58                       // padded rows/cols (1-halo each side)
#define PLANE (PROW*PROW*32)          // u16 per (b,cb) plane = 107648
#define PLANEB (PROW*PROW*64)         // bytes per (b,cb) plane = 215296
#define NSLOT 348                     // 6*58 real slots per staged window
#define QSLOT 350                     // slots incl. 2 dummy pad slots per q-plane
#define QSTRIDE (QSLOT*16)            // 5600 B per q-plane in LDS (kg banks {0,24,16,8})
#define NPIECE (4*QSLOT)              // 1400 16B pieces per buffer
#define BUFB (4*QSTRIDE)              // 22400 B per LDS buffer

typedef unsigned short u16;
typedef unsigned int uint32;
typedef __attribute__((ext_vector_type(8))) short bf16x8;
typedef __attribute__((ext_vector_type(4))) float f32x4;

__device__ __forceinline__ u16 f2bf(float f) {
    union { float f; uint32 u; } v; v.f = f;
    uint32 r = v.u + 0x7FFF + ((v.u >> 16) & 1);
    return (u16)(r >> 16);
}

__device__ __forceinline__ void gload16(const void* g, void* l) {
    __builtin_amdgcn_global_load_lds(
        (const __attribute__((address_space(1))) unsigned int*)g,
        (__attribute__((address_space(3))) unsigned int*)l, 16, 0, 0);
}

// ---------------- Stage 1: fused transpose->bf16 (zero-padded) + mix pooling ----
__global__ __launch_bounds__(256) void trans_pool(const float* __restrict__ x,
                                                  u16* __restrict__ xt,
                                                  float* __restrict__ pooled) {
    const int cb = blockIdx.x, b = blockIdx.y;
    const int tid = threadIdx.x;
    const int lane = tid & 63, wave = tid >> 6;
    const float* xp = x + ((size_t)b * CC + cb * 32) * SP;
    u16* xtb = xt + (size_t)(b * 8 + cb) * PLANE;

    // zero the 228 halo slots
    if (tid < 228) {
        int slot;
        if (tid < 58)       slot = tid;                       // row 0
        else if (tid < 116) slot = 57 * 58 + (tid - 58);      // row 57
        else if (tid < 172) slot = (tid - 116 + 1) * 58;      // col 0, rows 1..56
        else                slot = (tid - 172 + 1) * 58 + 57; // col 57, rows 1..56
        bf16x8 z = {};
        #pragma unroll
        for (int j = 0; j < 4; ++j)
            *(bf16x8*)&xtb[(size_t)slot * 32 + j * 8] = z;
    }

    float psum[32], pmax[32];
    #pragma unroll
    for (int c = 0; c < 32; ++c) { psum[c] = 0.f; pmax[c] = -INFINITY; }

    for (int p0 = 0; p0 < SP; p0 += 256) {
        const int p = p0 + tid;
        const bool v = p < SP;
        const int pc = v ? p : (SP - 1);
        u16 ob[32];
        #pragma unroll
        for (int c = 0; c < 32; ++c) {
            const float vv = xp[(size_t)c * SP + pc];
            if (v) { psum[c] += vv; pmax[c] = fmaxf(pmax[c], vv); }
            ob[c] = f2bf(vv);
        }
        if (v) {
            const int slot = (p / 56 + 1) * 58 + (p % 56 + 1);
            #pragma unroll
            for (int j = 0; j < 4; ++j)
                *(bf16x8*)&xtb[(size_t)slot * 32 + j * 8] = *(bf16x8*)&ob[j * 8];
        }
    }
    #pragma unroll
    for (int c = 0; c < 32; ++c) {
        #pragma unroll
        for (int off = 32; off >= 1; off >>= 1) {
            psum[c] += __shfl_xor(psum[c], off, 64);
            pmax[c] = fmaxf(pmax[c], __shfl_xor(pmax[c], off, 64));
        }
    }
    __shared__ float ssum[4][32];
    __shared__ float smax[4][32];
    if (lane == 0) {
        #pragma unroll
        for (int c = 0; c < 32; ++c) { ssum[wave][c] = psum[c]; smax[wave][c] = pmax[c]; }
    }
    __syncthreads();
    if (tid < 32) {
        const float s = ssum[0][tid] + ssum[1][tid] + ssum[2][tid] + ssum[3][tid];
        const float m = fmaxf(fmaxf(smax[0][tid], smax[1][tid]),
                              fmaxf(smax[2][tid], smax[3][tid]));
        pooled[b * (2 * CC) + cb * 32 + tid]      = s / (float)SP;
        pooled[b * (2 * CC) + CC + cb * 32 + tid] = m;
    }
}

// ---------------- Stage 2: attention MLP + softmax + agg bias ----------------
__global__ __launch_bounds__(256) void attn_kernel(const float* __restrict__ pooled,
                                                   const float* __restrict__ w1,
                                                   const float* __restrict__ w2,
                                                   const float* __restrict__ b2,
                                                   const float* __restrict__ bias_k,
                                                   float* __restrict__ attn,
                                                   float* __restrict__ agg_b) {
    const int b = blockIdx.x;
    const int tid = threadIdx.x;
    __shared__ float p[2 * CC];
    __shared__ float h[HID];
    __shared__ float a[KK];
    for (int i = tid; i < 2 * CC; i += 256) p[i] = pooled[b * 2 * CC + i];
    __syncthreads();
    if (tid < HID) {
        float s = 0.f;
        const float* w1r = w1 + (size_t)tid * (2 * CC);
        for (int c = 0; c < 2 * CC; ++c) s = fmaf(p[c], w1r[c], s);
        h[tid] = fmaxf(s, 0.f);
    }
    __syncthreads();
    if (tid == 0) {
        float lg[KK];
        float m = -INFINITY;
        for (int k = 0; k < KK; ++k) {
            float s = b2[k];
            for (int i = 0; i < HID; ++i) s = fmaf(h[i], w2[k * HID + i], s);
            lg[k] = s / TEMP;
            m = fmaxf(m, lg[k]);
        }
        float den = 0.f;
        for (int k = 0; k < KK; ++k) { lg[k] = expf(lg[k] - m); den += lg[k]; }
        for (int k = 0; k < KK; ++k) { a[k] = lg[k] / den; attn[b * KK + k] = a[k]; }
    }
    __syncthreads();
    if (tid < OO) {
        float s = 0.f;
        #pragma unroll
        for (int k = 0; k < KK; ++k) s = fmaf(a[k], bias_k[k * OO + tid], s);
        agg_b[b * OO + tid] = s;
    }
}

// ---------------- Stage 2b: aggregate weights -> bf16, layout wT[b][uv][o][c] ----
__global__ __launch_bounds__(256) void agg_kernel(const float* __restrict__ weight,
                                                  const float* __restrict__ attn,
                                                  u16* __restrict__ wT) {
    const int o = blockIdx.x;
    const int c = threadIdx.x;
    __shared__ float at[BB * KK];
    if (threadIdx.x < BB * KK) at[threadIdx.x] = attn[threadIdx.x];
    __syncthreads();
    float w[KK][9];
    #pragma unroll
    for (int k = 0; k < KK; ++k)
        #pragma unroll
        for (int uv = 0; uv < 9; ++uv)
            w[k][uv] = weight[(size_t)((k * OO + o) * CC + c) * 9 + uv];
    for (int b = 0; b < BB; ++b) {
        const float a0 = at[b*KK+0], a1 = at[b*KK+1], a2 = at[b*KK+2], a3 = at[b*KK+3];
        #pragma unroll
        for (int uv = 0; uv < 9; ++uv) {
            float s = a0 * w[0][uv] + a1 * w[1][uv] + a2 * w[2][uv] + a3 * w[3][uv];
            wT[(size_t)((b * 9 + uv) * OO + o) * CC + c] = f2bf(s);
        }
    }
}

// ---------------- Stage 3: MFMA implicit-GEMM conv — 8-wave TLP build ----------------
// Grid 896 (XCD-pinned), block 512 threads = 8 waves (4M x 2N), block tile
// 128o x 224p UNCHANGED (same staging traffic as R7/R11), wave 32o x 112p
// (M_rep=2 -> acc 56 AGPR; arch+acc ~124 <= 128). __launch_bounds__(512,4):
// 2 blocks/CU = 16 waves/CU = 4 waves/SIMD from two INDEPENDENTLY-barriered
// blocks — one block's MFMA phase overlaps the other's load phase. R12 showed
// occupancy alone (same per-wave stream) is not enough; R13 halves the
// per-wave dependency chain (2 A-loads + 7 B-reads + 14 MFMAs per phase) AND
// doubles independent waves per SIMD without duplicating staging.
// x staged via global_load_lds, linear LDS [q][350 slots]x16B, q-stride 5600B.
__global__ __launch_bounds__(512, 4) void conv_mfma(const u16* __restrict__ xt,
                                                    const u16* __restrict__ wT,
                                                    const float* __restrict__ agg_b,
                                                    float* __restrict__ out) {
    const int id   = blockIdx.x;
    const int g    = id >> 3;
    const int b    = (id & 7) + 8 * (g / 28);
    const int tile = g % 28;
    const int px   = tile % 14, oy = tile / 14;
    const int tid  = threadIdx.x;
    const int lane = tid & 63, wave = tid >> 6;   // 0..7
    const int wm = wave & 3, wn = wave >> 2;      // 4M x 2N
    const int l15 = lane & 15, kg = lane >> 4;
    const int p0 = px * 224;

    __shared__ char xs[2][BUFB];   // 2 x 22400 B

    // stage-piece map: piece i = k*512 + tid (i < 1400); LDS byte = i*16 (linear).
    // Global: q = i/350, slot = i%350 -> byte (px*232 + slot)*64 + q*16.
    uint32 soff[3]; bool sact[3];
    #pragma unroll
    for (int k = 0; k < 3; ++k) {
        const int i = k * 512 + tid;
        sact[k] = (i < NPIECE);
        const int q = i / QSLOT, slot = i % QSLOT;
        soff[k] = (uint32)((px * 232 + slot) * 64 + q * 16);
    }

    // B-read base byte per n-fragment: kg*QSTRIDE + S*16,
    // S = (n/56+1)*58 + n%56+1 (window-relative slot of output pixel)
    int bboff[7];
    #pragma unroll
    for (int nf = 0; nf < 7; ++nf) {
        const int n = wn * 112 + nf * 16 + l15;
        const int S = (n / 56 + 1) * 58 + (n % 56 + 1);
        bboff[nf] = kg * QSTRIDE + S * 16;
    }

    // A-operand: wT[b][uv][o][c], o = oy*128 + wm*32 + mf*16 + l15, c = c0 + kg*8
    const u16* wTb = wT + (size_t)b * 9 * OO * CC
                        + (size_t)(oy * 128 + wm * 32 + l15) * CC + kg * 8;

    f32x4 acc[2][7];
    #pragma unroll
    for (int mf = 0; mf < 2; ++mf)
        #pragma unroll
        for (int nf = 0; nf < 7; ++nf)
            acc[mf][nf] = (f32x4)0.f;

    const char* xgb = (const char*)xt + (size_t)(b * 8) * PLANEB;

    // prologue: stage chunk 0 into buf0 (exec-masked per lane; max byte 22384)
    #pragma unroll
    for (int k = 0; k < 3; ++k)
        if (sact[k]) gload16(xgb + soff[k], &xs[0][k * 8192 + wave * 1024]);
    __syncthreads();

    for (int cb = 0; cb < 8; ++cb) {
        const char* R = xs[cb & 1];
        char* W = xs[(cb & 1) ^ 1];
        const char* xg_next = xgb + (size_t)(cb + 1) * PLANEB;
        const int c0 = cb * 32;

        #pragma unroll
        for (int uv = 0; uv < 9; ++uv) {
            // spread next-chunk staging across phases 0..2
            if (uv < 3 && cb < 7) {
                if (sact[uv]) gload16(xg_next + soff[uv], &W[uv * 8192 + wave * 1024]);
            }
            bf16x8 av[2];
            #pragma unroll
            for (int mf = 0; mf < 2; ++mf)
                av[mf] = *(const bf16x8*)(wTb + (size_t)uv * OO * CC + mf * 16 * CC + c0);
            const int dby = ((uv / 3 - 1) * 58 + (uv % 3 - 1)) * 16;
            __builtin_amdgcn_s_setprio(1);
            #pragma unroll
            for (int nf = 0; nf < 7; ++nf) {
                const bf16x8 bv = *(const bf16x8*)(R + bboff[nf] + dby);
                #pragma unroll
                for (int mf = 0; mf < 2; ++mf)
                    acc[mf][nf] = __builtin_amdgcn_mfma_f32_16x16x32_bf16(av[mf], bv, acc[mf][nf], 0, 0, 0);
            }
            __builtin_amdgcn_s_setprio(0);
        }
        __syncthreads();   // staging queue already consumed; releases W
    }

    // epilogue: D row = kg*4 + r (-> o), col = l15 (-> p)
    const int obase = oy * 128 + wm * 32;
    float* outb = out + (size_t)b * OO * SP;
    #pragma unroll
    for (int mf = 0; mf < 2; ++mf) {
        #pragma unroll
        for (int r = 0; r < 4; ++r) {
            const int o = obase + mf * 16 + kg * 4 + r;
            const float bias = agg_b[b * OO + o];
            #pragma unroll
            for (int nf = 0; nf < 7; ++nf) {
                const int p = p0 + wn * 112 + nf * 16 + l15;
                outb[(size_t)o * SP + p] = acc[mf][nf][r] + bias;
            }
        }
    }
}

extern "C" void kernel_launch(void* const* d_in, const int* in_sizes, int n_in,
                              void* d_out, int out_size, void* d_ws, size_t ws_size,
                              hipStream_t stream) {
    const float* x      = (const float*)d_in[0];
    const float* weight = (const float*)d_in[1];
    const float* bias_k = (const float*)d_in[2];
    const float* w1     = (const float*)d_in[3];
    const float* w2     = (const float*)d_in[4];
    const float* b2     = (const float*)d_in[5];
    float* out = (float*)d_out;

    // workspace: x_t padded bf16 (55.1 MB) | wT bf16 (37.75 MB) | fp32 scratch
    u16* x_t = (u16*)d_ws;
    u16* wT  = x_t + (size_t)BB * 8 * PLANE;
    float* ws_f   = (float*)(wT + (size_t)BB * 9 * OO * CC);
    float* pooled = ws_f;
    float* attn   = ws_f + BB * 2 * CC;
    float* agg_b  = attn + BB * KK;

    trans_pool<<<dim3(8, BB), 256, 0, stream>>>(x, x_t, pooled);
    attn_kernel<<<BB, 256, 0, stream>>>(pooled, w1, w2, b2, bias_k, attn, agg_b);
    agg_kernel<<<OO, 256, 0, stream>>>(weight, attn, wT);
    conv_mfma<<<896, 512, 0, stream>>>(x_t, wT, agg_b, out);
}

// Round 14
// 207.031 us; speedup vs baseline: 1.1740x; 1.1222x over previous
//
#include <hip/hip_runtime.h>
#include <math.h>

#define BB 32
#define CC 256
#define OO 256
#define HW 56
#define SP (HW*HW)      // 3136
#define KK 4
#define HID 129
#define TEMP 34.0f
#define PROW 58                       // padded rows/cols (1-halo each side)
#define PLANE (PROW*PROW*32)          // u16 per (b,cb) plane = 107648
#define PLANEB (PROW*PROW*64)         // bytes per (b,cb) plane = 215296
#define NSLOT 348                     // 6*58 real slots per staged window
#define QSLOT 350                     // slots incl. 2 dummy pad slots per q-plane
#define QSTRIDE (QSLOT*16)            // 5600 B per q-plane in LDS
#define NPIECE (4*QSLOT)              // 1400 real 16B pieces per x buffer
#define XA_B 8192                     // A-subtile buffer (128o x 32c bf16)
#define XB_B 24576                    // x-window buffer (padded to 1536 pieces)

typedef unsigned short u16;
typedef unsigned int uint32;
typedef __attribute__((ext_vector_type(8))) short bf16x8;
typedef __attribute__((ext_vector_type(4))) float f32x4;

#define WAITVM(n) asm volatile("s_waitcnt vmcnt(" #n ")" ::: "memory")
#define WAITLGKM() asm volatile("s_waitcnt lgkmcnt(0)" ::: "memory")

__device__ __forceinline__ u16 f2bf(float f) {
    union { float f; uint32 u; } v; v.f = f;
    uint32 r = v.u + 0x7FFF + ((v.u >> 16) & 1);
    return (u16)(r >> 16);
}

__device__ __forceinline__ void gload16(const void* g, void* l) {
    __builtin_amdgcn_global_load_lds(
        (const __attribute__((address_space(1))) unsigned int*)g,
        (__attribute__((address_space(3))) unsigned int*)l, 16, 0, 0);
}

// ---------------- Stage 1: fused transpose->bf16 (zero-padded) + mix pooling ----
__global__ __launch_bounds__(256) void trans_pool(const float* __restrict__ x,
                                                  u16* __restrict__ xt,
                                                  float* __restrict__ pooled) {
    const int cb = blockIdx.x, b = blockIdx.y;
    const int tid = threadIdx.x;
    const int lane = tid & 63, wave = tid >> 6;
    const float* xp = x + ((size_t)b * CC + cb * 32) * SP;
    u16* xtb = xt + (size_t)(b * 8 + cb) * PLANE;

    // zero the 228 halo slots
    if (tid < 228) {
        int slot;
        if (tid < 58)       slot = tid;                       // row 0
        else if (tid < 116) slot = 57 * 58 + (tid - 58);      // row 57
        else if (tid < 172) slot = (tid - 116 + 1) * 58;      // col 0, rows 1..56
        else                slot = (tid - 172 + 1) * 58 + 57; // col 57, rows 1..56
        bf16x8 z = {};
        #pragma unroll
        for (int j = 0; j < 4; ++j)
            *(bf16x8*)&xtb[(size_t)slot * 32 + j * 8] = z;
    }

    float psum[32], pmax[32];
    #pragma unroll
    for (int c = 0; c < 32; ++c) { psum[c] = 0.f; pmax[c] = -INFINITY; }

    for (int p0 = 0; p0 < SP; p0 += 256) {
        const int p = p0 + tid;
        const bool v = p < SP;
        const int pc = v ? p : (SP - 1);
        u16 ob[32];
        #pragma unroll
        for (int c = 0; c < 32; ++c) {
            const float vv = xp[(size_t)c * SP + pc];
            if (v) { psum[c] += vv; pmax[c] = fmaxf(pmax[c], vv); }
            ob[c] = f2bf(vv);
        }
        if (v) {
            const int slot = (p / 56 + 1) * 58 + (p % 56 + 1);
            #pragma unroll
            for (int j = 0; j < 4; ++j)
                *(bf16x8*)&xtb[(size_t)slot * 32 + j * 8] = *(bf16x8*)&ob[j * 8];
        }
    }
    #pragma unroll
    for (int c = 0; c < 32; ++c) {
        #pragma unroll
        for (int off = 32; off >= 1; off >>= 1) {
            psum[c] += __shfl_xor(psum[c], off, 64);
            pmax[c] = fmaxf(pmax[c], __shfl_xor(pmax[c], off, 64));
        }
    }
    __shared__ float ssum[4][32];
    __shared__ float smax[4][32];
    if (lane == 0) {
        #pragma unroll
        for (int c = 0; c < 32; ++c) { ssum[wave][c] = psum[c]; smax[wave][c] = pmax[c]; }
    }
    __syncthreads();
    if (tid < 32) {
        const float s = ssum[0][tid] + ssum[1][tid] + ssum[2][tid] + ssum[3][tid];
        const float m = fmaxf(fmaxf(smax[0][tid], smax[1][tid]),
                              fmaxf(smax[2][tid], smax[3][tid]));
        pooled[b * (2 * CC) + cb * 32 + tid]      = s / (float)SP;
        pooled[b * (2 * CC) + CC + cb * 32 + tid] = m;
    }
}

// ---------------- Stage 2: attention MLP + softmax + agg bias ----------------
__global__ __launch_bounds__(256) void attn_kernel(const float* __restrict__ pooled,
                                                   const float* __restrict__ w1,
                                                   const float* __restrict__ w2,
                                                   const float* __restrict__ b2,
                                                   const float* __restrict__ bias_k,
                                                   float* __restrict__ attn,
                                                   float* __restrict__ agg_b) {
    const int b = blockIdx.x;
    const int tid = threadIdx.x;
    __shared__ float p[2 * CC];
    __shared__ float h[HID];
    __shared__ float a[KK];
    for (int i = tid; i < 2 * CC; i += 256) p[i] = pooled[b * 2 * CC + i];
    __syncthreads();
    if (tid < HID) {
        float s = 0.f;
        const float* w1r = w1 + (size_t)tid * (2 * CC);
        for (int c = 0; c < 2 * CC; ++c) s = fmaf(p[c], w1r[c], s);
        h[tid] = fmaxf(s, 0.f);
    }
    __syncthreads();
    if (tid == 0) {
        float lg[KK];
        float m = -INFINITY;
        for (int k = 0; k < KK; ++k) {
            float s = b2[k];
            for (int i = 0; i < HID; ++i) s = fmaf(h[i], w2[k * HID + i], s);
            lg[k] = s / TEMP;
            m = fmaxf(m, lg[k]);
        }
        float den = 0.f;
        for (int k = 0; k < KK; ++k) { lg[k] = expf(lg[k] - m); den += lg[k]; }
        for (int k = 0; k < KK; ++k) { a[k] = lg[k] / den; attn[b * KK + k] = a[k]; }
    }
    __syncthreads();
    if (tid < OO) {
        float s = 0.f;
        #pragma unroll
        for (int k = 0; k < KK; ++k) s = fmaf(a[k], bias_k[k * OO + tid], s);
        agg_b[b * OO + tid] = s;
    }
}

// ---------------- Stage 2b: aggregate weights -> bf16 ----------------
// Layout wT2[b][uv][cb][oy][kg][128 ol][8 cl]: the (uv,cb,oy) A-subtile is a
// contiguous 8192B region, linear-stageable via global_load_lds, and the
// ds_read pattern [kg][ol][8c] is quarter-wave-contiguous (2-way banks, free).
__global__ __launch_bounds__(256) void agg_kernel(const float* __restrict__ weight,
                                                  const float* __restrict__ attn,
                                                  u16* __restrict__ wT2) {
    const int o = blockIdx.x;
    const int c = threadIdx.x;
    __shared__ float at[BB * KK];
    if (threadIdx.x < BB * KK) at[threadIdx.x] = attn[threadIdx.x];
    __syncthreads();
    float w[KK][9];
    #pragma unroll
    for (int k = 0; k < KK; ++k)
        #pragma unroll
        for (int uv = 0; uv < 9; ++uv)
            w[k][uv] = weight[(size_t)((k * OO + o) * CC + c) * 9 + uv];
    const int cb = c >> 5, kg = (c >> 3) & 3, cl = c & 7;
    const int oy = o >> 7, ol = o & 127;
    const size_t sub = (size_t)kg * 1024 + ol * 8 + cl;
    for (int b = 0; b < BB; ++b) {
        const float a0 = at[b*KK+0], a1 = at[b*KK+1], a2 = at[b*KK+2], a3 = at[b*KK+3];
        #pragma unroll
        for (int uv = 0; uv < 9; ++uv) {
            float s = a0 * w[0][uv] + a1 * w[1][uv] + a2 * w[2][uv] + a3 * w[3][uv];
            const size_t region = (((size_t)b * 9 + uv) * 8 + cb) * 2 + oy;
            wT2[region * 4096 + sub] = f2bf(s);
        }
    }
}

// ---------------- Stage 3: MFMA implicit-GEMM conv — 8-phase counted-vmcnt ----
// Grid 896 (XCD-pinned), 512 thr = 8 waves (4M x 2N), block 128o x 224p, wave
// 32o x 112p (M_rep=2, acc 56 AGPR). 72 K-steps j = cb*9+uv; per step ONE raw
// s_barrier + counted vmcnt (never 0 mid-loop):
//   vmcnt(VM[uv]) ; s_barrier ; ds_read 2A+7B ; issue A-stage(j+2) [+x at uv<3]
//   ; lgkmcnt(0)+sched_barrier ; setprio(1) 14 MFMA setprio(0)
// A: 3-deep LDS ring (8KB/step, distance-2, ring idx uv%3 chunk-invariant).
// B: x-window dbuf (24.5KB), 3 exec-uniform pieces staged at uv=0,1,2.
// Dummy tail stages keep per-wave vmcnt counts exact everywhere.
__global__ __launch_bounds__(512, 4) void conv_mfma(const u16* __restrict__ xt,
                                                    const u16* __restrict__ wT2,
                                                    const float* __restrict__ agg_b,
                                                    float* __restrict__ out) {
    const int id   = blockIdx.x;
    const int g    = id >> 3;
    const int b    = (id & 7) + 8 * (g / 28);
    const int tile = g % 28;
    const int px   = tile % 14, oy = tile / 14;
    const int tid  = threadIdx.x;
    const int lane = tid & 63, wave = tid >> 6;   // 0..7
    const int wm = wave & 3, wn = wave >> 2;      // 4M x 2N
    const int l15 = lane & 15, kg = lane >> 4;
    const int p0 = px * 224;

    __shared__ char XA[3][XA_B];   // 24576 B
    __shared__ char XB[2][XB_B];   // 49152 B

    // x stage-piece map (3 pieces/thread, clamped so every wave issues uniformly)
    uint32 soff[3];
    #pragma unroll
    for (int k = 0; k < 3; ++k) {
        int i = k * 512 + tid;
        if (i >= NPIECE) i = NPIECE - 1;
        const int q = i / QSLOT, slot = i % QSLOT;
        soff[k] = (uint32)((px * 232 + slot) * 64 + q * 16);
    }

    // B-read base byte per n-fragment
    int bboff[7];
    #pragma unroll
    for (int nf = 0; nf < 7; ++nf) {
        const int n = wn * 112 + nf * 16 + l15;
        const int S = (n / 56 + 1) * 58 + (n % 56 + 1);
        bboff[nf] = kg * QSTRIDE + S * 16;
    }

    // A ds_read byte within XA buffer: [kg][ol][8c], ol = wm*32 + mf*16 + l15
    const int aoff0 = kg * 2048 + (wm * 32 + l15) * 16;        // mf=0
    const int aoff1 = aoff0 + 16 * 16;                          // mf=1

    const char* xgb = (const char*)xt + (size_t)(b * 8) * PLANEB;
    const char* wAb = (const char*)wT2 + (size_t)b * 9 * 8 * 2 * 8192
                     + (size_t)oy * 8192;                       // + (uv*8+cb)*2*8192
    const size_t tb = (size_t)tid * 16;

    f32x4 acc[2][7];
    #pragma unroll
    for (int mf = 0; mf < 2; ++mf)
        #pragma unroll
        for (int nf = 0; nf < 7; ++nf)
            acc[mf][nf] = (f32x4)0.f;

    // prologue: x chunk 0 -> XB[0]; A steps 0,1 -> XA[0],XA[1]
    #pragma unroll
    for (int k = 0; k < 3; ++k)
        gload16(xgb + soff[k], &XB[0][k * 8192 + wave * 1024]);
    gload16(wAb + (size_t)(0 * 8 + 0) * 2 * 8192 + tb, &XA[0][wave * 1024]);
    gload16(wAb + (size_t)(1 * 8 + 0) * 2 * 8192 + tb, &XA[1][wave * 1024]);

    for (int cb = 0; cb < 8; ++cb) {
        const char* RB = XB[cb & 1];
        char* WB = XB[(cb & 1) ^ 1];
        const char* xg_next = xgb + (size_t)((cb + 1) & 7) * PLANEB;

        #pragma unroll
        for (int uv = 0; uv < 9; ++uv) {
            // counted wait: A(j) (+ whole x window when uv==0) landed; never 0
            if (uv == 2 || uv == 3) WAITVM(3);
            else if (uv == 1 || uv == 4) WAITVM(2);
            else WAITVM(1);
            __builtin_amdgcn_s_barrier();

            // ds_read: 2 A-frags + 7 B-frags
            const char* RA = XA[uv % 3];
            bf16x8 av0 = *(const bf16x8*)(RA + aoff0);
            bf16x8 av1 = *(const bf16x8*)(RA + aoff1);
            const int dby = ((uv / 3 - 1) * 58 + (uv % 3 - 1)) * 16;
            bf16x8 bv[7];
            #pragma unroll
            for (int nf = 0; nf < 7; ++nf)
                bv[nf] = *(const bf16x8*)(RB + bboff[nf] + dby);

            // issue stages: A for step j+2 (dummy at tail), x piece at uv<3
            {
                const int uv_s = (uv + 2 < 9) ? uv + 2 : uv - 7;
                const int cb_s = (uv + 2 < 9) ? cb : ((cb + 1) & 7);
                gload16(wAb + (size_t)(uv_s * 8 + cb_s) * 2 * 8192 + tb,
                        &XA[(uv + 2) % 3][wave * 1024]);
            }
            if (uv < 3)
                gload16(xg_next + soff[uv], &WB[uv * 8192 + wave * 1024]);

            WAITLGKM();
            __builtin_amdgcn_sched_barrier(0);
            __builtin_amdgcn_s_setprio(1);
            #pragma unroll
            for (int nf = 0; nf < 7; ++nf) {
                acc[0][nf] = __builtin_amdgcn_mfma_f32_16x16x32_bf16(av0, bv[nf], acc[0][nf], 0, 0, 0);
                acc[1][nf] = __builtin_amdgcn_mfma_f32_16x16x32_bf16(av1, bv[nf], acc[1][nf], 0, 0, 0);
            }
            __builtin_amdgcn_s_setprio(0);
        }
    }

    // epilogue: D row = kg*4 + r (-> o), col = l15 (-> p)
    const int obase = oy * 128 + wm * 32;
    float* outb = out + (size_t)b * OO * SP;
    #pragma unroll
    for (int mf = 0; mf < 2; ++mf) {
        #pragma unroll
        for (int r = 0; r < 4; ++r) {
            const int o = obase + mf * 16 + kg * 4 + r;
            const float bias = agg_b[b * OO + o];
            #pragma unroll
            for (int nf = 0; nf < 7; ++nf) {
                const int p = p0 + wn * 112 + nf * 16 + l15;
                outb[(size_t)o * SP + p] = acc[mf][nf][r] + bias;
            }
        }
    }
}

extern "C" void kernel_launch(void* const* d_in, const int* in_sizes, int n_in,
                              void* d_out, int out_size, void* d_ws, size_t ws_size,
                              hipStream_t stream) {
    const float* x      = (const float*)d_in[0];
    const float* weight = (const float*)d_in[1];
    const float* bias_k = (const float*)d_in[2];
    const float* w1     = (const float*)d_in[3];
    const float* w2     = (const float*)d_in[4];
    const float* b2     = (const float*)d_in[5];
    float* out = (float*)d_out;

    // workspace: x_t padded bf16 (55.1 MB) | wT2 bf16 (37.75 MB) | fp32 scratch
    u16* x_t = (u16*)d_ws;
    u16* wT2 = x_t + (size_t)BB * 8 * PLANE;
    float* ws_f   = (float*)(wT2 + (size_t)BB * 9 * OO * CC);
    float* pooled = ws_f;
    float* attn   = ws_f + BB * 2 * CC;
    float* agg_b  = attn + BB * KK;

    trans_pool<<<dim3(8, BB), 256, 0, stream>>>(x, x_t, pooled);
    attn_kernel<<<BB, 256, 0, stream>>>(pooled, w1, w2, b2, bias_k, attn, agg_b);
    agg_kernel<<<OO, 256, 0, stream>>>(weight, attn, wT2);
    conv_mfma<<<896, 512, 0, stream>>>(x_t, wT2, agg_b, out);
}

// Round 15
// 205.840 us; speedup vs baseline: 1.1808x; 1.0058x over previous
//
#include <hip/hip_runtime.h>
#include <math.h>

#define BB 32
#define CC 256
#define OO 256
#define HW 56
#define SP (HW*HW)      // 3136
#define KK 4
#define HID 129
#define TEMP 34.0f
#define PROW 58                       // padded rows/cols (1-halo each side)
#define PLANE (PROW*PROW*32)          // u16 per (b,cb) plane = 107648
#define PLANEB (PROW*PROW*64)         // bytes per (b,cb) plane = 215296
#define NSLOT 348                     // 6*58 real slots per staged window
#define QSLOT 350                     // slots incl. 2 dummy pad slots per q-plane
#define QSTRIDE (QSLOT*16)            // 5600 B per q-plane in LDS
#define NPIECE (4*QSLOT)              // 1400 real 16B pieces per x buffer
#define XA_B 8192                     // A-subtile buffer (128o x 32c bf16)
#define XB_B 24576                    // x-window buffer (padded to 1536 pieces)

typedef unsigned short u16;
typedef unsigned int uint32;
typedef __attribute__((ext_vector_type(8))) short bf16x8;
typedef __attribute__((ext_vector_type(4))) float f32x4;

#define WAITVM(n) asm volatile("s_waitcnt vmcnt(" #n ")" ::: "memory")
#define WAITLGKM() asm volatile("s_waitcnt lgkmcnt(0)" ::: "memory")

__device__ __forceinline__ u16 f2bf(float f) {
    union { float f; uint32 u; } v; v.f = f;
    uint32 r = v.u + 0x7FFF + ((v.u >> 16) & 1);
    return (u16)(r >> 16);
}

__device__ __forceinline__ void gload16(const void* g, void* l) {
    __builtin_amdgcn_global_load_lds(
        (const __attribute__((address_space(1))) unsigned int*)g,
        (__attribute__((address_space(3))) unsigned int*)l, 16, 0, 0);
}

// ---------------- Stage 1: fused transpose->bf16 (zero-padded) + mix pooling ----
__global__ __launch_bounds__(256) void trans_pool(const float* __restrict__ x,
                                                  u16* __restrict__ xt,
                                                  float* __restrict__ pooled) {
    const int cb = blockIdx.x, b = blockIdx.y;
    const int tid = threadIdx.x;
    const int lane = tid & 63, wave = tid >> 6;
    const float* xp = x + ((size_t)b * CC + cb * 32) * SP;
    u16* xtb = xt + (size_t)(b * 8 + cb) * PLANE;

    // zero the 228 halo slots
    if (tid < 228) {
        int slot;
        if (tid < 58)       slot = tid;                       // row 0
        else if (tid < 116) slot = 57 * 58 + (tid - 58);      // row 57
        else if (tid < 172) slot = (tid - 116 + 1) * 58;      // col 0, rows 1..56
        else                slot = (tid - 172 + 1) * 58 + 57; // col 57, rows 1..56
        bf16x8 z = {};
        #pragma unroll
        for (int j = 0; j < 4; ++j)
            *(bf16x8*)&xtb[(size_t)slot * 32 + j * 8] = z;
    }

    float psum[32], pmax[32];
    #pragma unroll
    for (int c = 0; c < 32; ++c) { psum[c] = 0.f; pmax[c] = -INFINITY; }

    for (int p0 = 0; p0 < SP; p0 += 256) {
        const int p = p0 + tid;
        const bool v = p < SP;
        const int pc = v ? p : (SP - 1);
        u16 ob[32];
        #pragma unroll
        for (int c = 0; c < 32; ++c) {
            const float vv = xp[(size_t)c * SP + pc];
            if (v) { psum[c] += vv; pmax[c] = fmaxf(pmax[c], vv); }
            ob[c] = f2bf(vv);
        }
        if (v) {
            const int slot = (p / 56 + 1) * 58 + (p % 56 + 1);
            #pragma unroll
            for (int j = 0; j < 4; ++j)
                *(bf16x8*)&xtb[(size_t)slot * 32 + j * 8] = *(bf16x8*)&ob[j * 8];
        }
    }
    #pragma unroll
    for (int c = 0; c < 32; ++c) {
        #pragma unroll
        for (int off = 32; off >= 1; off >>= 1) {
            psum[c] += __shfl_xor(psum[c], off, 64);
            pmax[c] = fmaxf(pmax[c], __shfl_xor(pmax[c], off, 64));
        }
    }
    __shared__ float ssum[4][32];
    __shared__ float smax[4][32];
    if (lane == 0) {
        #pragma unroll
        for (int c = 0; c < 32; ++c) { ssum[wave][c] = psum[c]; smax[wave][c] = pmax[c]; }
    }
    __syncthreads();
    if (tid < 32) {
        const float s = ssum[0][tid] + ssum[1][tid] + ssum[2][tid] + ssum[3][tid];
        const float m = fmaxf(fmaxf(smax[0][tid], smax[1][tid]),
                              fmaxf(smax[2][tid], smax[3][tid]));
        pooled[b * (2 * CC) + cb * 32 + tid]      = s / (float)SP;
        pooled[b * (2 * CC) + CC + cb * 32 + tid] = m;
    }
}

// ---------------- Stage 2: attention MLP + softmax + agg bias ----------------
__global__ __launch_bounds__(256) void attn_kernel(const float* __restrict__ pooled,
                                                   const float* __restrict__ w1,
                                                   const float* __restrict__ w2,
                                                   const float* __restrict__ b2,
                                                   const float* __restrict__ bias_k,
                                                   float* __restrict__ attn,
                                                   float* __restrict__ agg_b) {
    const int b = blockIdx.x;
    const int tid = threadIdx.x;
    __shared__ float p[2 * CC];
    __shared__ float h[HID];
    __shared__ float a[KK];
    for (int i = tid; i < 2 * CC; i += 256) p[i] = pooled[b * 2 * CC + i];
    __syncthreads();
    if (tid < HID) {
        float s = 0.f;
        const float* w1r = w1 + (size_t)tid * (2 * CC);
        for (int c = 0; c < 2 * CC; ++c) s = fmaf(p[c], w1r[c], s);
        h[tid] = fmaxf(s, 0.f);
    }
    __syncthreads();
    if (tid == 0) {
        float lg[KK];
        float m = -INFINITY;
        for (int k = 0; k < KK; ++k) {
            float s = b2[k];
            for (int i = 0; i < HID; ++i) s = fmaf(h[i], w2[k * HID + i], s);
            lg[k] = s / TEMP;
            m = fmaxf(m, lg[k]);
        }
        float den = 0.f;
        for (int k = 0; k < KK; ++k) { lg[k] = expf(lg[k] - m); den += lg[k]; }
        for (int k = 0; k < KK; ++k) { a[k] = lg[k] / den; attn[b * KK + k] = a[k]; }
    }
    __syncthreads();
    if (tid < OO) {
        float s = 0.f;
        #pragma unroll
        for (int k = 0; k < KK; ++k) s = fmaf(a[k], bias_k[k * OO + tid], s);
        agg_b[b * OO + tid] = s;
    }
}

// ---------------- Stage 2b: aggregate weights -> bf16, layout wT[b][uv][o][c] ----
// Coalesced: lane = c, per-wave 128B stores (R14's scattered wT2 writes cost 26us).
__global__ __launch_bounds__(256) void agg_kernel(const float* __restrict__ weight,
                                                  const float* __restrict__ attn,
                                                  u16* __restrict__ wT) {
    const int o = blockIdx.x;
    const int c = threadIdx.x;
    __shared__ float at[BB * KK];
    if (threadIdx.x < BB * KK) at[threadIdx.x] = attn[threadIdx.x];
    __syncthreads();
    float w[KK][9];
    #pragma unroll
    for (int k = 0; k < KK; ++k)
        #pragma unroll
        for (int uv = 0; uv < 9; ++uv)
            w[k][uv] = weight[(size_t)((k * OO + o) * CC + c) * 9 + uv];
    for (int b = 0; b < BB; ++b) {
        const float a0 = at[b*KK+0], a1 = at[b*KK+1], a2 = at[b*KK+2], a3 = at[b*KK+3];
        #pragma unroll
        for (int uv = 0; uv < 9; ++uv) {
            float s = a0 * w[0][uv] + a1 * w[1][uv] + a2 * w[2][uv] + a3 * w[3][uv];
            wT[(size_t)((b * 9 + uv) * OO + o) * CC + c] = f2bf(s);
        }
    }
}

// ---------------- Stage 3: MFMA implicit-GEMM conv — 8-phase counted-vmcnt ----
// Grid 896 (XCD-pinned), 512 thr = 8 waves (4M x 2N), block 128o x 224p, wave
// 32o x 112p (M_rep=2, acc 56 AGPR). 72 K-steps j = cb*9+uv; per step ONE raw
// s_barrier + counted vmcnt (never 0 mid-loop):
//   vmcnt(VM[uv]) ; s_barrier ; ds_read 2A+7B ; issue A-stage(j+2) [+x at uv<3]
//   ; lgkmcnt(0)+sched_barrier ; setprio(1) 14 MFMA setprio(0)
// A: 3-deep LDS ring (8KB/step, distance-2, ring idx uv%3 chunk-invariant),
//    staged from wT[b][uv][o][c] via PER-LANE global addresses (m104: the
//    global side of global_load_lds is per-lane; LDS dest stays linear tid*16).
//    LDS layout [kg][ol][8c]: lane tid -> kg=tid>>7, ol=tid&127,
//    global off = (oy*128+ol)*512 + kg*16 (+ uv*131072 + cb*64 per step).
// B: x-window dbuf (24.5KB), 3 exec-uniform pieces staged at uv=0,1,2.
// Dummy tail stages keep per-wave vmcnt counts exact everywhere.
__global__ __launch_bounds__(512, 4) void conv_mfma(const u16* __restrict__ xt,
                                                    const u16* __restrict__ wT,
                                                    const float* __restrict__ agg_b,
                                                    float* __restrict__ out) {
    const int id   = blockIdx.x;
    const int g    = id >> 3;
    const int b    = (id & 7) + 8 * (g / 28);
    const int tile = g % 28;
    const int px   = tile % 14, oy = tile / 14;
    const int tid  = threadIdx.x;
    const int lane = tid & 63, wave = tid >> 6;   // 0..7
    const int wm = wave & 3, wn = wave >> 2;      // 4M x 2N
    const int l15 = lane & 15, kg = lane >> 4;
    const int p0 = px * 224;

    __shared__ char XA[3][XA_B];   // 24576 B
    __shared__ char XB[2][XB_B];   // 49152 B

    // x stage-piece map (3 pieces/thread, clamped so every wave issues uniformly)
    uint32 soff[3];
    #pragma unroll
    for (int k = 0; k < 3; ++k) {
        int i = k * 512 + tid;
        if (i >= NPIECE) i = NPIECE - 1;
        const int q = i / QSLOT, slot = i % QSLOT;
        soff[k] = (uint32)((px * 232 + slot) * 64 + q * 16);
    }

    // B-read base byte per n-fragment
    int bboff[7];
    #pragma unroll
    for (int nf = 0; nf < 7; ++nf) {
        const int n = wn * 112 + nf * 16 + l15;
        const int S = (n / 56 + 1) * 58 + (n % 56 + 1);
        bboff[nf] = kg * QSTRIDE + S * 16;
    }

    // A ds_read byte within XA buffer: [kg][ol][8c], ol = wm*32 + mf*16 + l15
    const int aoff0 = kg * 2048 + (wm * 32 + l15) * 16;        // mf=0
    const int aoff1 = aoff0 + 16 * 16;                          // mf=1

    // A stage: per-lane global byte offset into wT[b][uv][o][c]
    const char* xgb = (const char*)xt + (size_t)(b * 8) * PLANEB;
    const char* wAb = (const char*)wT + (size_t)b * 9 * OO * CC * 2;
    const size_t aglane = (size_t)((oy * 128 + (tid & 127)) * 512 + (tid >> 7) * 16);

    f32x4 acc[2][7];
    #pragma unroll
    for (int mf = 0; mf < 2; ++mf)
        #pragma unroll
        for (int nf = 0; nf < 7; ++nf)
            acc[mf][nf] = (f32x4)0.f;

    // prologue: x chunk 0 -> XB[0]; A steps (uv=0,cb=0), (uv=1,cb=0) -> XA[0],XA[1]
    #pragma unroll
    for (int k = 0; k < 3; ++k)
        gload16(xgb + soff[k], &XB[0][k * 8192 + wave * 1024]);
    gload16(wAb + (size_t)0 * 131072 + 0 * 64 + aglane, &XA[0][wave * 1024]);
    gload16(wAb + (size_t)1 * 131072 + 0 * 64 + aglane, &XA[1][wave * 1024]);

    for (int cb = 0; cb < 8; ++cb) {
        const char* RB = XB[cb & 1];
        char* WB = XB[(cb & 1) ^ 1];
        const char* xg_next = xgb + (size_t)((cb + 1) & 7) * PLANEB;

        #pragma unroll
        for (int uv = 0; uv < 9; ++uv) {
            // counted wait: A(j) (+ whole x window when uv==0) landed; never 0
            if (uv == 2 || uv == 3) WAITVM(3);
            else if (uv == 1 || uv == 4) WAITVM(2);
            else WAITVM(1);
            __builtin_amdgcn_s_barrier();

            // ds_read: 2 A-frags + 7 B-frags
            const char* RA = XA[uv % 3];
            bf16x8 av0 = *(const bf16x8*)(RA + aoff0);
            bf16x8 av1 = *(const bf16x8*)(RA + aoff1);
            const int dby = ((uv / 3 - 1) * 58 + (uv % 3 - 1)) * 16;
            bf16x8 bv[7];
            #pragma unroll
            for (int nf = 0; nf < 7; ++nf)
                bv[nf] = *(const bf16x8*)(RB + bboff[nf] + dby);

            // issue stages: A for step j+2 (dummy at tail), x piece at uv<3
            {
                const int uv_s = (uv + 2 < 9) ? uv + 2 : uv - 7;
                const int cb_s = (uv + 2 < 9) ? cb : ((cb + 1) & 7);
                gload16(wAb + (size_t)uv_s * 131072 + cb_s * 64 + aglane,
                        &XA[(uv + 2) % 3][wave * 1024]);
            }
            if (uv < 3)
                gload16(xg_next + soff[uv], &WB[uv * 8192 + wave * 1024]);

            WAITLGKM();
            __builtin_amdgcn_sched_barrier(0);
            __builtin_amdgcn_s_setprio(1);
            #pragma unroll
            for (int nf = 0; nf < 7; ++nf) {
                acc[0][nf] = __builtin_amdgcn_mfma_f32_16x16x32_bf16(av0, bv[nf], acc[0][nf], 0, 0, 0);
                acc[1][nf] = __builtin_amdgcn_mfma_f32_16x16x32_bf16(av1, bv[nf], acc[1][nf], 0, 0, 0);
            }
            __builtin_amdgcn_s_setprio(0);
        }
    }

    // epilogue: D row = kg*4 + r (-> o), col = l15 (-> p)
    const int obase = oy * 128 + wm * 32;
    float* outb = out + (size_t)b * OO * SP;
    #pragma unroll
    for (int mf = 0; mf < 2; ++mf) {
        #pragma unroll
        for (int r = 0; r < 4; ++r) {
            const int o = obase + mf * 16 + kg * 4 + r;
            const float bias = agg_b[b * OO + o];
            #pragma unroll
            for (int nf = 0; nf < 7; ++nf) {
                const int p = p0 + wn * 112 + nf * 16 + l15;
                outb[(size_t)o * SP + p] = acc[mf][nf][r] + bias;
            }
        }
    }
}

extern "C" void kernel_launch(void* const* d_in, const int* in_sizes, int n_in,
                              void* d_out, int out_size, void* d_ws, size_t ws_size,
                              hipStream_t stream) {
    const float* x      = (const float*)d_in[0];
    const float* weight = (const float*)d_in[1];
    const float* bias_k = (const float*)d_in[2];
    const float* w1     = (const float*)d_in[3];
    const float* w2     = (const float*)d_in[4];
    const float* b2     = (const float*)d_in[5];
    float* out = (float*)d_out;

    // workspace: x_t padded bf16 (55.1 MB) | wT bf16 (37.75 MB) | fp32 scratch
    u16* x_t = (u16*)d_ws;
    u16* wT  = x_t + (size_t)BB * 8 * PLANE;
    float* ws_f   = (float*)(wT + (size_t)BB * 9 * OO * CC);
    float* pooled = ws_f;
    float* attn   = ws_f + BB * 2 * CC;
    float* agg_b  = attn + BB * KK;

    trans_pool<<<dim3(8, BB), 256, 0, stream>>>(x, x_t, pooled);
    attn_kernel<<<BB, 256, 0, stream>>>(pooled, w1, w2, b2, bias_k, attn, agg_b);
    agg_kernel<<<OO, 256, 0, stream>>>(weight, attn, wT);
    conv_mfma<<<896, 512, 0, stream>>>(x_t, wT, agg_b, out);
}